// Round 5
// baseline (59.146 us; speedup 1.0000x reference)
//
#include <hip/hip_runtime.h>
#include <math.h>

#define B_   8
#define C_   4
#define H_   96
#define W_   96
#define HW_  9216
#define NBINS 18052              // exact d2 values 0..18050, plus bin 18051 == +inf
#define INFBIN 18051
#define NH32 ((NBINS + 1) / 2)   // 9026 packed words, 2 x u16 counters each

// One block per (b, c, dir). dir==0: fwd (query = pred set, target = label set)
//                            dir==1: rev (query = label set, target = pred set)
__global__ __launch_bounds__(256) void hd_main(const float* __restrict__ preds,
                                               const int*   __restrict__ labels,
                                               float* __restrict__ frws)
{
    __shared__ unsigned long long qmask[HW_ / 64];   // 1152 B query mask bits
    __shared__ unsigned long long tmask[HW_ / 64];   // 1152 B target mask bits
    __shared__ unsigned short g2u[HW_];              // 18432 B per-row 1D dist^2 (u16)
    __shared__ unsigned int   h32[NH32];             // 36104 B packed 16-bit histogram
    __shared__ int partials[256];                    // 1024 B
    __shared__ int sc[5];                            // nT, nQ, n0, svlo, svhi

    const int id  = blockIdx.x;       // 0..63
    const int dir = id & 1;
    const int bc  = id >> 1;
    const int b   = bc >> 2;
    const int c   = bc & 3;
    const int tid = threadIdx.x;
    const int lane = tid & 63;

    const float* Pb = preds  + (size_t)b * C_ * HW_;
    const int*   Lb = labels + (size_t)b * HW_;

    for (int i = tid; i < NH32; i += 256) h32[i] = 0u;
    if (tid == 0) { sc[0] = 0; sc[1] = 0; sc[2] = 0; sc[3] = -1; sc[4] = -1; }
    __syncthreads();

    // ---- Step 1: fused argmax + both masks (+ counts, + |q ∩ t| = d2==0 count) ----
    {
        int myT = 0, myQ = 0, myN0 = 0;
        #pragma unroll 4
        for (int k = 0; k < HW_ / 256; ++k) {
            const int p = k * 256 + tid;
            float v0 = Pb[p];
            float v1 = Pb[HW_ + p];
            float v2 = Pb[2 * HW_ + p];
            float v3 = Pb[3 * HW_ + p];
            int bi = 0; float bv = v0;
            if (v1 > bv) { bv = v1; bi = 1; }   // strict '>' keeps first max (jnp.argmax)
            if (v2 > bv) { bv = v2; bi = 2; }
            if (v3 > bv) { bv = v3; bi = 3; }
            const int lab = Lb[p];
            const bool pm = (bi == c);          // predicted-class mask
            const bool lm = (lab == c);         // label-class mask
            const bool qm = dir ? lm : pm;
            const bool tm = dir ? pm : lm;
            const unsigned long long qb = __ballot(qm);
            const unsigned long long tb = __ballot(tm);
            if (lane == 0) {
                qmask[p >> 6] = qb;
                tmask[p >> 6] = tb;
                myQ  += __popcll(qb);
                myT  += __popcll(tb);
                myN0 += __popcll(qb & tb);      // query pixels with d2 == 0
            }
        }
        if (lane == 0) {
            if (myT)  atomicAdd(&sc[0], myT);
            if (myQ)  atomicAdd(&sc[1], myQ);
            if (myN0) atomicAdd(&sc[2], myN0);
        }
    }
    __syncthreads();

    const int tEmpty = (sc[0] == 0);

    // ---- Step 2: horizontal nearest-set-bit distance via clz/ctz, per pixel ----
    // Row y = 96 bits: A = pixels x=0..63, Bw = pixels x=64..95 (low 32 bits).
    for (int k = 0; k < HW_ / 256; ++k) {
        const int p = k * 256 + tid;
        const int y = p / W_;
        const int x = p - y * W_;
        const int bp = y * W_;                 // row start bit position
        const int wi = bp >> 6;
        const int sh = bp & 63;                // 0 (even y) or 32 (odd y)
        const unsigned long long w0 = tmask[wi];
        const unsigned long long w1 = tmask[wi + 1];
        unsigned long long A, Bw;
        if (sh == 0) { A = w0;                       Bw = w1 & 0xFFFFFFFFull; }
        else         { A = (w0 >> 32) | (w1 << 32); Bw = w1 >> 32; }

        int dl = 1000, dr = 1000;
        if (x < 64) {
            const unsigned long long ml = A & ((2ull << x) - 1ull);   // bits <= x (x=63 wraps to ~0)
            if (ml) dl = x - (63 - __builtin_clzll(ml));
            const unsigned long long mr = A & ~((1ull << x) - 1ull);  // bits >= x
            if (mr)      dr = __builtin_ctzll(mr) - x;
            else if (Bw) dr = 64 + __builtin_ctzll(Bw) - x;
        } else {
            const int xb = x - 64;                                    // 0..31
            const unsigned long long ml = Bw & ((2ull << xb) - 1ull);
            if (ml)     dl = x - (64 + 63 - __builtin_clzll(ml));
            else if (A) dl = x - (63 - __builtin_clzll(A));
            const unsigned long long mr = Bw & ~((1ull << xb) - 1ull);
            if (mr) dr = 64 + __builtin_ctzll(mr) - x;
        }
        const int g = min(dl, dr);
        g2u[p] = (g >= 96) ? (unsigned short)40000     // row empty: > any real d2
                           : (unsigned short)(g * g);
    }
    __syncthreads();

    // ---- Step 3: exact outward early-exit column scan, query pixels only ----
    // d2(y,x) = min_r (y-r)^2 + g2(r,x). Scanning off = |y-r| outward, once
    // off^2 >= best no farther row can improve (g2 >= 0) -> exact early exit.
    for (int k = 0; k < HW_ / 256; ++k) {
        const int p = k * 256 + tid;
        const int qbit = (int)((qmask[p >> 6] >> (p & 63)) & 1ull);
        if (!qbit) continue;
        if (tEmpty) {
            atomicAdd(&h32[INFBIN >> 1], 1u << ((INFBIN & 1) << 4));
            continue;
        }
        const int tbit = (int)((tmask[p >> 6] >> (p & 63)) & 1ull);
        if (tbit) continue;                              // d2 == 0, counted via popcount
        const int y = p / W_;
        const int x = p - y * W_;
        int best = (int)g2u[p];                          // off = 0 row
        for (int off = 1; off < H_; ++off) {
            const int o2 = off * off;
            if (o2 >= best) break;
            const int r1 = y - off;
            const int r2 = y + off;
            if (r1 >= 0) best = min(best, o2 + (int)g2u[r1 * W_ + x]);
            if (r2 < H_) best = min(best, o2 + (int)g2u[r2 * W_ + x]);
        }
        atomicAdd(&h32[best >> 1], 1u << ((best & 1) << 4));  // best in [1, 18050]
    }
    __syncthreads();

    if (tid == 0 && !tEmpty && sc[2] > 0)
        h32[0] += (unsigned int)sc[2];                   // bin 0 lives in low half of word 0
    __syncthreads();

    // ---- Step 4: exact rank selection from packed histogram ----
    const int n = sc[1];
    const int CHUNK = (NBINS + 255) / 256;               // 71
    const int base_i = tid * CHUNK;
    int lsum = 0;
    for (int j = 0; j < CHUNK; ++j) {
        const int i = base_i + j;
        if (i < NBINS) lsum += (int)((h32[i >> 1] >> ((i & 1) << 4)) & 0xFFFFu);
    }
    partials[tid] = lsum;
    __syncthreads();
    if (tid == 0) {
        int run = 0;
        for (int t = 0; t < 256; ++t) { const int v = partials[t]; partials[t] = run; run += v; }
    }
    __syncthreads();

    int nm1 = n - 1; if (nm1 < 0) nm1 = 0;
    const float posf = 0.95f * (float)nm1;               // matches (q/100)*f32(n-1)
    const int lo = (int)floorf(posf);
    const int hi = (int)ceilf(posf);
    const float frac = posf - (float)lo;

    int run = partials[tid];
    for (int j = 0; j < CHUNK; ++j) {
        const int i = base_i + j;
        if (i >= NBINS) break;
        const int h = (int)((h32[i >> 1] >> ((i & 1) << 4)) & 0xFFFFu);
        if (h > 0) {
            const int nrun = run + h;
            if (run <= lo && lo < nrun) sc[3] = i;       // exactly one thread hits each
            if (run <= hi && hi < nrun) sc[4] = i;
            run = nrun;
        }
    }
    __syncthreads();

    if (tid == 0) {
        const int svlo = sc[3], svhi = sc[4];
        const float vlo = (svlo < 0 || svlo == INFBIN) ? __builtin_inff()
                                                       : (float)sqrt((double)svlo);
        const float vhi = (svhi < 0 || svhi == INFBIN) ? __builtin_inff()
                                                       : (float)sqrt((double)svhi);
        // literal reference arithmetic (inf*0 -> nan semantics preserved)
        frws[id] = vlo * (1.0f - frac) + vhi * frac;
    }
}

__global__ __launch_bounds__(64) void hd_fin(const float* __restrict__ frws,
                                             float* __restrict__ out)
{
    __shared__ float fr[64];
    const int tid = threadIdx.x;
    fr[tid] = frws[tid];                                 // parallel load (64 values)
    __syncthreads();
    if (tid == 0) {
        float F[4], R[4], M[4];
        for (int c = 0; c < 4; ++c) {
            if (c == 0) { F[c] = R[c] = M[c] = 0.0f; continue; }  // IGNORE class
            float sf = 0.0f, sr = 0.0f, sm = 0.0f;
            for (int b = 0; b < 8; ++b) {
                const float f = fr[((b * 4 + c) << 1) + 0];
                const float r = fr[((b * 4 + c) << 1) + 1];
                sf += f; sr += r;
                float m = f > r ? f : r;
                if (f != f || r != r) m = f + r;        // NaN-propagating maximum
                sm += m;
            }
            F[c] = sf / 8.0f; R[c] = sr / 8.0f; M[c] = sm / 8.0f;
        }
        // out = concat(MHD, FHD, RHD), each [c0..c3, mean(all), mean(excl c0)]
        float* o = out;
        o[0] = M[0]; o[1] = M[1]; o[2] = M[2]; o[3] = M[3];
        o[4] = (M[0] + M[1] + M[2] + M[3]) / 4.0f;
        o[5] = (M[1] + M[2] + M[3]) / 3.0f;
        o += 6;
        o[0] = F[0]; o[1] = F[1]; o[2] = F[2]; o[3] = F[3];
        o[4] = (F[0] + F[1] + F[2] + F[3]) / 4.0f;
        o[5] = (F[1] + F[2] + F[3]) / 3.0f;
        o += 6;
        o[0] = R[0]; o[1] = R[1]; o[2] = R[2]; o[3] = R[3];
        o[4] = (R[0] + R[1] + R[2] + R[3]) / 4.0f;
        o[5] = (R[1] + R[2] + R[3]) / 3.0f;
    }
}

extern "C" void kernel_launch(void* const* d_in, const int* in_sizes, int n_in,
                              void* d_out, int out_size, void* d_ws, size_t ws_size,
                              hipStream_t stream)
{
    const float* preds  = (const float*)d_in[0];
    const int*   labels = (const int*)d_in[1];
    float* frws = (float*)d_ws;                  // 64 floats staging (f,r per b,c)

    hipLaunchKernelGGL(hd_main, dim3(B_ * C_ * 2), dim3(256), 0, stream,
                       preds, labels, frws);
    hipLaunchKernelGGL(hd_fin, dim3(1), dim3(64), 0, stream,
                       frws, (float*)d_out);
}

// Round 6
// 26.271 us; speedup vs baseline: 2.2514x; 2.2514x over previous
//
#include <hip/hip_runtime.h>
#include <math.h>

#define B_   8
#define C_   4
#define H_   96
#define W_   96
#define HW_  9216
#define NBINS 18052              // exact d2 values 0..18050, plus bin 18051 == +inf
#define INFBIN 18051
#define NH32 ((NBINS + 1) / 2)   // 9026 packed words, 2 x u16 counters each
#define NT   1024                // threads per block (16 waves)

// One block per (b, c, dir). dir==0: fwd (query = pred set, target = label set)
//                            dir==1: rev (query = label set, target = pred set)
__global__ __launch_bounds__(NT) void hd_main(const float* __restrict__ preds,
                                              const int*   __restrict__ labels,
                                              float* __restrict__ frws)
{
    __shared__ unsigned long long qmask[HW_ / 64];   // 1152 B query mask bits
    __shared__ unsigned long long tmask[HW_ / 64];   // 1152 B target mask bits
    __shared__ unsigned short g2u[HW_];              // 18432 B per-row 1D dist^2 (u16)
    __shared__ unsigned int   h32[NH32];             // 36104 B packed 16-bit histogram
    __shared__ int wsum[16];                         // 64 B wave-scan sums
    __shared__ int sc[5];                            // nT, nQ, n0, svlo, svhi

    const int id  = blockIdx.x;       // 0..63
    const int dir = id & 1;
    const int bc  = id >> 1;
    const int b   = bc >> 2;
    const int c   = bc & 3;
    const int tid = threadIdx.x;
    const int lane = tid & 63;
    const int wid  = tid >> 6;        // 0..15

    const float* Pb = preds  + (size_t)b * C_ * HW_;
    const int*   Lb = labels + (size_t)b * HW_;

    for (int i = tid; i < NH32; i += NT) h32[i] = 0u;
    if (tid == 0) { sc[0] = 0; sc[1] = 0; sc[2] = 0; sc[3] = -1; sc[4] = -1; }
    __syncthreads();

    // ---- Step 1: fused argmax + both masks (+ counts, + |q ∩ t| = d2==0 count) ----
    {
        int myT = 0, myQ = 0, myN0 = 0;
        #pragma unroll 3
        for (int k = 0; k < HW_ / NT; ++k) {
            const int p = k * NT + tid;
            float v0 = Pb[p];
            float v1 = Pb[HW_ + p];
            float v2 = Pb[2 * HW_ + p];
            float v3 = Pb[3 * HW_ + p];
            int bi = 0; float bv = v0;
            if (v1 > bv) { bv = v1; bi = 1; }   // strict '>' keeps first max (jnp.argmax)
            if (v2 > bv) { bv = v2; bi = 2; }
            if (v3 > bv) { bv = v3; bi = 3; }
            const int lab = Lb[p];
            const bool pm = (bi == c);          // predicted-class mask
            const bool lm = (lab == c);         // label-class mask
            const bool qm = dir ? lm : pm;
            const bool tm = dir ? pm : lm;
            const unsigned long long qb = __ballot(qm);
            const unsigned long long tb = __ballot(tm);
            if (lane == 0) {
                qmask[p >> 6] = qb;
                tmask[p >> 6] = tb;
                myQ  += __popcll(qb);
                myT  += __popcll(tb);
                myN0 += __popcll(qb & tb);      // query pixels with d2 == 0
            }
        }
        if (lane == 0) {
            if (myT)  atomicAdd(&sc[0], myT);
            if (myQ)  atomicAdd(&sc[1], myQ);
            if (myN0) atomicAdd(&sc[2], myN0);
        }
    }
    __syncthreads();

    const int tEmpty = (sc[0] == 0);

    // ---- Step 2: horizontal nearest-set-bit distance via clz/ctz, per pixel ----
    // Row y = 96 bits: A = pixels x=0..63, Bw = pixels x=64..95 (low 32 bits).
    for (int k = 0; k < HW_ / NT; ++k) {
        const int p = k * NT + tid;
        const int y = p / W_;
        const int x = p - y * W_;
        const int bp = y * W_;                 // row start bit position
        const int wi = bp >> 6;
        const int sh = bp & 63;                // 0 (even y) or 32 (odd y)
        const unsigned long long w0 = tmask[wi];
        const unsigned long long w1 = tmask[wi + 1];
        unsigned long long A, Bw;
        if (sh == 0) { A = w0;                       Bw = w1 & 0xFFFFFFFFull; }
        else         { A = (w0 >> 32) | (w1 << 32); Bw = w1 >> 32; }

        int dl = 1000, dr = 1000;
        if (x < 64) {
            const unsigned long long ml = A & ((2ull << x) - 1ull);   // bits <= x (x=63 wraps to ~0)
            if (ml) dl = x - (63 - __builtin_clzll(ml));
            const unsigned long long mr = A & ~((1ull << x) - 1ull);  // bits >= x
            if (mr)      dr = __builtin_ctzll(mr) - x;
            else if (Bw) dr = 64 + __builtin_ctzll(Bw) - x;
        } else {
            const int xb = x - 64;                                    // 0..31
            const unsigned long long ml = Bw & ((2ull << xb) - 1ull);
            if (ml)     dl = x - (64 + 63 - __builtin_clzll(ml));
            else if (A) dl = x - (63 - __builtin_clzll(A));
            const unsigned long long mr = Bw & ~((1ull << xb) - 1ull);
            if (mr) dr = 64 + __builtin_ctzll(mr) - x;
        }
        const int g = min(dl, dr);
        g2u[p] = (g >= 96) ? (unsigned short)40000     // row empty: > any real d2
                           : (unsigned short)(g * g);
    }
    __syncthreads();

    // ---- Step 3: exact outward early-exit column scan, query pixels only ----
    // d2(y,x) = min_r (y-r)^2 + g2(r,x). Scanning off = |y-r| outward, once
    // off^2 >= best no farther row can improve (g2 >= 0) -> exact early exit.
    for (int k = 0; k < HW_ / NT; ++k) {
        const int p = k * NT + tid;
        const int qbit = (int)((qmask[p >> 6] >> (p & 63)) & 1ull);
        if (!qbit) continue;
        if (tEmpty) {
            atomicAdd(&h32[INFBIN >> 1], 1u << ((INFBIN & 1) << 4));
            continue;
        }
        const int tbit = (int)((tmask[p >> 6] >> (p & 63)) & 1ull);
        if (tbit) continue;                              // d2 == 0, counted via popcount
        const int y = p / W_;
        const int x = p - y * W_;
        int best = (int)g2u[p];                          // off = 0 row
        for (int off = 1; off < H_; ++off) {
            const int o2 = off * off;
            if (o2 >= best) break;
            const int r1 = y - off;
            const int r2 = y + off;
            if (r1 >= 0) best = min(best, o2 + (int)g2u[r1 * W_ + x]);
            if (r2 < H_) best = min(best, o2 + (int)g2u[r2 * W_ + x]);
        }
        atomicAdd(&h32[best >> 1], 1u << ((best & 1) << 4));  // best in [1, 18050]
    }
    __syncthreads();

    if (tid == 0 && !tEmpty && sc[2] > 0)
        h32[0] += (unsigned int)sc[2];                   // bin 0 lives in low half of word 0
    __syncthreads();

    // ---- Step 4: exact rank selection, fully parallel prefix scan ----
    const int n = sc[1];
    const int CHUNK = (NBINS + NT - 1) / NT;             // 18
    const int base_i = tid * CHUNK;
    int lsum = 0;
    #pragma unroll
    for (int j = 0; j < CHUNK; ++j) {
        const int i = base_i + j;
        if (i < NBINS) lsum += (int)((h32[i >> 1] >> ((i & 1) << 4)) & 0xFFFFu);
    }
    // wave-level inclusive scan of lsum
    int incl = lsum;
    #pragma unroll
    for (int d = 1; d < 64; d <<= 1) {
        const int t = __shfl_up(incl, d, 64);
        if (lane >= d) incl += t;
    }
    if (lane == 63) wsum[wid] = incl;
    __syncthreads();
    if (wid == 0) {                                      // scan the 16 wave sums
        const int w = (lane < 16) ? wsum[lane] : 0;
        int wincl = w;
        #pragma unroll
        for (int d = 1; d < 16; d <<= 1) {
            const int t = __shfl_up(wincl, d, 64);
            if (lane >= d) wincl += t;
        }
        if (lane < 16) wsum[lane] = wincl - w;           // exclusive wave prefix
    }
    __syncthreads();

    int nm1 = n - 1; if (nm1 < 0) nm1 = 0;
    const float posf = 0.95f * (float)nm1;               // matches (q/100)*f32(n-1)
    const int lo = (int)floorf(posf);
    const int hi = (int)ceilf(posf);
    const float frac = posf - (float)lo;

    int run = (incl - lsum) + wsum[wid];                 // exclusive prefix over bins < base_i
    #pragma unroll
    for (int j = 0; j < CHUNK; ++j) {
        const int i = base_i + j;
        if (i >= NBINS) break;
        const int h = (int)((h32[i >> 1] >> ((i & 1) << 4)) & 0xFFFFu);
        if (h > 0) {
            const int nrun = run + h;
            if (run <= lo && lo < nrun) sc[3] = i;       // exactly one thread hits each
            if (run <= hi && hi < nrun) sc[4] = i;
            run = nrun;
        }
    }
    __syncthreads();

    if (tid == 0) {
        const int svlo = sc[3], svhi = sc[4];
        const float vlo = (svlo < 0 || svlo == INFBIN) ? __builtin_inff()
                                                       : (float)sqrt((double)svlo);
        const float vhi = (svhi < 0 || svhi == INFBIN) ? __builtin_inff()
                                                       : (float)sqrt((double)svhi);
        // literal reference arithmetic (inf*0 -> nan semantics preserved)
        frws[id] = vlo * (1.0f - frac) + vhi * frac;
    }
}

__global__ __launch_bounds__(64) void hd_fin(const float* __restrict__ frws,
                                             float* __restrict__ out)
{
    __shared__ float fr[64];
    const int tid = threadIdx.x;
    fr[tid] = frws[tid];                                 // parallel load (64 values)
    __syncthreads();
    if (tid == 0) {
        float F[4], R[4], M[4];
        for (int c = 0; c < 4; ++c) {
            if (c == 0) { F[c] = R[c] = M[c] = 0.0f; continue; }  // IGNORE class
            float sf = 0.0f, sr = 0.0f, sm = 0.0f;
            for (int b = 0; b < 8; ++b) {
                const float f = fr[((b * 4 + c) << 1) + 0];
                const float r = fr[((b * 4 + c) << 1) + 1];
                sf += f; sr += r;
                float m = f > r ? f : r;
                if (f != f || r != r) m = f + r;        // NaN-propagating maximum
                sm += m;
            }
            F[c] = sf / 8.0f; R[c] = sr / 8.0f; M[c] = sm / 8.0f;
        }
        // out = concat(MHD, FHD, RHD), each [c0..c3, mean(all), mean(excl c0)]
        float* o = out;
        o[0] = M[0]; o[1] = M[1]; o[2] = M[2]; o[3] = M[3];
        o[4] = (M[0] + M[1] + M[2] + M[3]) / 4.0f;
        o[5] = (M[1] + M[2] + M[3]) / 3.0f;
        o += 6;
        o[0] = F[0]; o[1] = F[1]; o[2] = F[2]; o[3] = F[3];
        o[4] = (F[0] + F[1] + F[2] + F[3]) / 4.0f;
        o[5] = (F[1] + F[2] + F[3]) / 3.0f;
        o += 6;
        o[0] = R[0]; o[1] = R[1]; o[2] = R[2]; o[3] = R[3];
        o[4] = (R[0] + R[1] + R[2] + R[3]) / 4.0f;
        o[5] = (R[1] + R[2] + R[3]) / 3.0f;
    }
}

extern "C" void kernel_launch(void* const* d_in, const int* in_sizes, int n_in,
                              void* d_out, int out_size, void* d_ws, size_t ws_size,
                              hipStream_t stream)
{
    const float* preds  = (const float*)d_in[0];
    const int*   labels = (const int*)d_in[1];
    float* frws = (float*)d_ws;                  // 64 floats staging (f,r per b,c)

    hipLaunchKernelGGL(hd_main, dim3(B_ * C_ * 2), dim3(NT), 0, stream,
                       preds, labels, frws);
    hipLaunchKernelGGL(hd_fin, dim3(1), dim3(64), 0, stream,
                       frws, (float*)d_out);
}